// Round 7
// baseline (22069.299 us; speedup 1.0000x reference)
//
#include <hip/hip_runtime.h>
#include <hip/hip_bf16.h>

typedef __hip_bfloat16 bf16;

constexpr int NN = 307, TT = 12, BB = 32, HH = 64, EE = 10, HEADS = 4, HD = 16, HORIZON = 12;

// ---------------- staged fp32 input offsets ----------------
constexpr int S_SRC = 0,       S_EMB = 117888,  S_GW0 = 120958,  S_GB0 = 287358,
              S_UW0 = 288638,  S_UB0 = 371838,  S_GW1 = 372478,  S_GB1 = 700158,
              S_UW1 = 701438,  S_UB1 = 865278,  S_MLW = 865918,  S_MLB = 865982,
              S_WQ  = 866046,  S_BQ  = 870142,  S_WK  = 870206,  S_BK  = 874302,
              S_WV  = 874366,  S_BV  = 878462,  S_WO  = 878526,  S_BO  = 882622,
              S_FW1 = 882686,  S_FB1 = 948222,  S_FW2 = 949246,  S_FB2 = 1014782,
              S_L1G = 1014846, S_L1B = 1014910, S_L2G = 1014974, S_L2B = 1015038,
              S_WS  = 1015102, S_WT  = 1034750, S_CW  = 1054398, S_CB  = 1055166;

// ---------------- fp32 work regions ----------------
constexpr size_t OFF_A    = 1055178;   // 307*307
constexpr size_t OFF_OUT0 = 1149427;   // [t][n][b][c] 12*307*2048
constexpr size_t OFF_H    = 8694259;   // [n][b][c] 307*2048
constexpr size_t OFF_ZH   = 9322995;
constexpr size_t OFF_R    = 9951731;
constexpr size_t OFF_AGG  = 10580467;  // A@H then A@ZH (barrier-separated)
constexpr size_t OFF_AX0  = 11209203;  // [t][n][b] 12*307*32
constexpr size_t OFF_AX1  = 11327091;  // [t][n][b][c] 12*307*2048
constexpr size_t OFF_PE   = 18871923;  // 12*64
constexpr size_t OFF_OLN  = 18872691;
constexpr size_t OFF_O2   = 19501427;
constexpr size_t OFF_WB   = 20130164;  // fp32 reordered per-node GRU weights

// Reordered weight blocks (fp32; bf16 storage fails: scan amplifies to 0.19 absmax — r3)
constexpr size_t G0X = OFF_WB +        0;  // 307*2*128
constexpr size_t G0H = OFF_WB +    78592;  // 307*128*128
constexpr size_t BG0 = OFF_WB +  5108480;  // 307*128
constexpr size_t U0X = OFF_WB +  5147776;  // 307*2*64
constexpr size_t U0H = OFF_WB +  5187072;  // 307*128*64
constexpr size_t BU0 = OFF_WB +  7702016;  // 307*64
constexpr size_t G1X = OFF_WB +  7721664;  // 307*128*128
constexpr size_t G1H = OFF_WB + 12751552;  // 307*128*128
constexpr size_t BG1 = OFF_WB + 17781440;  // 307*128
constexpr size_t U1X = OFF_WB + 17820736;  // 307*128*64
constexpr size_t U1H = OFF_WB + 20335680;  // 307*128*64
constexpr size_t BU1 = OFF_WB + 22850624;  // 307*64
// r6->r7 FIX: these two regions were undersized (15,083,520 / 7,541,760) -> OOB write
// 12KB past g_buf, clobbering g_bar_* -> gridbar deadlock -> abort. Correct sizes:
// GXP = 12*307*32*128 = 15,089,664 ; UXP = 12*307*32*64 = 7,544,832. +4K guard pad.
constexpr size_t OFF_GXP = OFF_WB + 22870272;       // [t][n][b][128] preact x-part (bias folded)
constexpr size_t OFF_UXP = OFF_GXP + 15089664;      // [t][n][b][64]
constexpr size_t G_TOTAL = OFF_UXP + 7544832 + 4096;

__device__ float g_buf[G_TOTAL];
__device__ int g_flag;   // 1 = inputs are bf16, 0 = fp32

// ---------------- software grid barrier (512 blocks, 2/CU guaranteed residency) ----------------
constexpr int NBLK = 512;
__device__ unsigned g_bar_cnt;
__device__ unsigned g_bar_gen;

__device__ __forceinline__ void gridbar() {
    __syncthreads();
    __threadfence();                          // publish this block's writes device-wide
    if (threadIdx.x == 0) {
        unsigned gen = __hip_atomic_load(&g_bar_gen, __ATOMIC_RELAXED, __HIP_MEMORY_SCOPE_AGENT);
        unsigned a = __hip_atomic_fetch_add(&g_bar_cnt, 1u, __ATOMIC_ACQ_REL, __HIP_MEMORY_SCOPE_AGENT);
        if (a == (unsigned)(NBLK - 1)) {
            __hip_atomic_store(&g_bar_cnt, 0u, __ATOMIC_RELAXED, __HIP_MEMORY_SCOPE_AGENT);
            __hip_atomic_store(&g_bar_gen, gen + 1u, __ATOMIC_RELEASE, __HIP_MEMORY_SCOPE_AGENT);
        } else {
            while (__hip_atomic_load(&g_bar_gen, __ATOMIC_ACQUIRE, __HIP_MEMORY_SCOPE_AGENT) == gen)
                __builtin_amdgcn_s_sleep(2);
        }
    }
    __syncthreads();
    __threadfence();                          // invalidate stale caches before reading
}

__device__ __forceinline__ float wave_sum(float v) {
    #pragma unroll
    for (int off = 32; off > 0; off >>= 1) v += __shfl_xor(v, off, 64);
    return v;
}

// ---------------- dtype detection ----------------
__global__ void k_detect(const void* emb_raw) {
    const bf16* p = (const bf16*)emb_raw;
    int lane = threadIdx.x;
    float v = __bfloat162float(p[lane]);
    bool plaus = (v == v) && (fabsf(v) <= 1e4f) && (v == 0.f || fabsf(v) >= 1e-4f);
    float c = wave_sum(plaus ? 1.f : 0.f);
    if (lane == 0) g_flag = (c >= 52.f) ? 1 : 0;
}

// ---------------- ingest all inputs as fp32 ----------------
struct PtrPack { const void* p[32]; };
__device__ const int D_CNT[32] = {117888,3070,166400,1280,83200,640,327680,1280,163840,640,
                                  64,64,4096,64,4096,64,4096,64,4096,64,
                                  65536,1024,65536,64,64,64,64,64,19648,19648,768,12};
__device__ const int D_OFF[32] = {S_SRC,S_EMB,S_GW0,S_GB0,S_UW0,S_UB0,S_GW1,S_GB1,S_UW1,S_UB1,
                                  S_MLW,S_MLB,S_WQ,S_BQ,S_WK,S_BK,S_WV,S_BV,S_WO,S_BO,
                                  S_FW1,S_FB1,S_FW2,S_FB2,S_L1G,S_L1B,S_L2G,S_L2B,S_WS,S_WT,S_CW,S_CB};
__device__ const int D_CHK[33] = {0,461,473,1123,1128,1453,1456,2736,2741,3381,3384,3385,3386,
                                  3402,3403,3419,3420,3436,3437,3453,3454,3710,3714,3970,3971,
                                  3972,3973,3974,3975,4052,4129,4132,4133};

__global__ void k_ingest(PtrPack pk) {
    int bid = blockIdx.x;
    int s = 0;
    while (s < 31 && bid >= D_CHK[s + 1]) s++;
    int i = (bid - D_CHK[s]) * 256 + threadIdx.x;
    if (i >= D_CNT[s]) return;
    float v;
    if (g_flag) v = __bfloat162float(((const bf16*)pk.p[s])[i]);
    else        v = ((const float*)pk.p[s])[i];
    g_buf[(size_t)D_OFF[s] + i] = v;
}

// ---------------- adjacency ----------------
__global__ void k_adj() {
    int n = blockIdx.x;
    int tid = threadIdx.x;            // 512
    __shared__ float en[EE];
    __shared__ float red[512];
    if (tid < EE) en[tid] = g_buf[S_EMB + n * EE + tid];
    __syncthreads();
    bool act = tid < NN;
    float d = 0.f;
    if (act) {
        #pragma unroll
        for (int e = 0; e < EE; e++) d += en[e] * g_buf[S_EMB + tid * EE + e];
        d = fmaxf(d, 0.f);
    }
    red[tid] = act ? d : -1e30f;
    __syncthreads();
    for (int s = 256; s > 0; s >>= 1) { if (tid < s) red[tid] = fmaxf(red[tid], red[tid + s]); __syncthreads(); }
    float mx = red[0];
    __syncthreads();
    float ex = act ? expf(d - mx) : 0.f;
    red[tid] = ex;
    __syncthreads();
    for (int s = 256; s > 0; s >>= 1) { if (tid < s) red[tid] += red[tid + s]; __syncthreads(); }
    float inv = 1.f / red[0];
    if (act) g_buf[OFF_A + (size_t)n * NN + tid] = ex * inv;
}

// ---------------- per-node GRU weights -> fp32, reordered into Wx/Wh blocks ----------------
__device__ const unsigned SEGC[9] = {0u,5108480u,5147776u,7702016u,7721664u,17781440u,17820736u,22850624u,22870272u};
__device__ const int SEGJ[8]      = {16640,128,8320,64,32768,128,16384,64};
__device__ const int SEGS[8]      = {S_GW0,S_GB0,S_UW0,S_UB0,S_GW1,S_GB1,S_UW1,S_UB1};

__global__ void k_nodew_all() {
    unsigned idx = blockIdx.x * 256u + threadIdx.x;
    if (idx >= 22870272u) return;
    int s = 0;
    while (s < 7 && idx >= SEGC[s + 1]) s++;
    unsigned rem = idx - SEGC[s];
    unsigned J = (unsigned)SEGJ[s];
    unsigned n = rem / J;
    unsigned j = rem - n * J;
    float acc = 0.f;
    const float* eb = g_buf + S_EMB + n * EE;
    const float* w  = g_buf + SEGS[s];
    #pragma unroll
    for (int e = 0; e < EE; e++) acc += eb[e] * w[(size_t)e * J + j];
    size_t dst;
    if (s == 0) {        // gw0: j = (k*65+i)*128+o
        unsigned o = j & 127, kk = j >> 7, k = kk / 65, i = kk % 65;
        dst = (i == 0) ? G0X + ((size_t)n * 2 + k) * 128 + o
                       : G0H + ((size_t)n * 128 + k * 64 + (i - 1)) * 128 + o;
    } else if (s == 1) { dst = BG0 + (size_t)n * 128 + j;
    } else if (s == 2) { // uw0: j = (k*65+i)*64+o
        unsigned o = j & 63, kk = j >> 6, k = kk / 65, i = kk % 65;
        dst = (i == 0) ? U0X + ((size_t)n * 2 + k) * 64 + o
                       : U0H + ((size_t)n * 128 + k * 64 + (i - 1)) * 64 + o;
    } else if (s == 3) { dst = BU0 + (size_t)n * 64 + j;
    } else if (s == 4) { // gw1: j = (k*128+i)*128+o
        unsigned o = j & 127, kk = j >> 7, k = kk >> 7, i = kk & 127;
        dst = (i < 64) ? G1X + ((size_t)n * 128 + k * 64 + i) * 128 + o
                       : G1H + ((size_t)n * 128 + k * 64 + (i - 64)) * 128 + o;
    } else if (s == 5) { dst = BG1 + (size_t)n * 128 + j;
    } else if (s == 6) { // uw1: j = (k*128+i)*64+o
        unsigned o = j & 63, kk = j >> 6, k = kk >> 7, i = kk & 127;
        dst = (i < 64) ? U1X + ((size_t)n * 128 + k * 64 + i) * 64 + o
                       : U1H + ((size_t)n * 128 + k * 64 + (i - 64)) * 64 + o;
    } else {             dst = BU1 + (size_t)n * 64 + j; }
    g_buf[dst] = acc;
}

// ---------------- positional embedding ----------------
__global__ void k_pe() {
    int tid = threadIdx.x;            // 768
    int t = tid >> 6, h = tid & 63;
    float ex = (float)(h & ~1) / 64.f;
    float ang = (float)t * powf(10000.f, -ex);
    g_buf[OFF_PE + tid] = (h & 1) ? cosf(ang) : sinf(ang);
}

__global__ void k_zero(size_t off, int cnt) {
    int i = blockIdx.x * 256 + threadIdx.x;
    if (i < cnt) g_buf[off + i] = 0.f;
}

// ---------------- AX0[t][n][b] = sum_m A[n,m] * src[b,t,m] ----------------
__global__ __launch_bounds__(256) void k_ax0() {
    int t = blockIdx.y;
    int n0 = blockIdx.x * 8;
    int b = threadIdx.x & 31, nl = threadIdx.x >> 5;
    __shared__ float As[8][68];
    __shared__ float xs[32][65];
    float acc = 0.f;
    for (int m0 = 0; m0 < NN; m0 += 64) {
        int jend = min(64, NN - m0);
        for (int idx = threadIdx.x; idx < 8 * 64; idx += 256) {
            int i = idx >> 6, jj = idx & 63;
            int n = n0 + i, m = m0 + jj;
            As[i][jj] = (n < NN && m < NN) ? g_buf[OFF_A + (size_t)n * NN + m] : 0.f;
        }
        for (int idx = threadIdx.x; idx < 32 * 64; idx += 256) {
            int bb = idx >> 6, jj = idx & 63;
            int m = m0 + jj;
            xs[bb][jj] = (m < NN) ? g_buf[S_SRC + ((size_t)bb * TT + t) * NN + m] : 0.f;
        }
        __syncthreads();
        for (int jj = 0; jj < jend; jj++) acc += As[nl][jj] * xs[b][jj];
        __syncthreads();
    }
    int n = n0 + nl;
    if (n < NN) g_buf[OFF_AX0 + ((size_t)t * NN + n) * 32 + b] = acc;
}

// ---------------- standalone agg GEMM (used for AX1, z=12 parallel) ----------------
__global__ __launch_bounds__(256) void k_aggmat(size_t srcOff, size_t dstOff, size_t srcTS, size_t dstTS) {
    int z = blockIdx.z;
    const float* __restrict__ srcp = g_buf + srcOff + (size_t)z * srcTS;
    float* __restrict__ dstp = g_buf + dstOff + (size_t)z * dstTS;
    int n0 = blockIdx.x * 64;
    int col0 = blockIdx.y * 64;
    int tid = threadIdx.x;
    int tn = tid >> 4, tc = tid & 15;
    __shared__ float As[32][68];
    __shared__ float Xs[32][64];
    float acc[4][4];
    #pragma unroll
    for (int i = 0; i < 4; i++)
        #pragma unroll
        for (int j = 0; j < 4; j++) acc[i][j] = 0.f;
    for (int k0 = 0; k0 < NN; k0 += 32) {
        for (int idx = tid; idx < 64 * 32; idx += 256) {
            int k = idx & 31, i = idx >> 5;
            int n = n0 + i, m = k0 + k;
            As[k][i] = (n < NN && m < NN) ? g_buf[OFF_A + (size_t)n * NN + m] : 0.f;
        }
        for (int idx = tid; idx < 32 * 64; idx += 256) {
            int c = idx & 63, k = idx >> 6;
            int m = k0 + k;
            Xs[k][c] = (m < NN) ? srcp[(size_t)m * 2048 + col0 + c] : 0.f;
        }
        __syncthreads();
        #pragma unroll
        for (int k = 0; k < 32; k++) {
            float4 a4 = *(const float4*)&As[k][tn * 4];
            float4 x4 = *(const float4*)&Xs[k][tc * 4];
            const float* aa = (const float*)&a4;
            const float* xx = (const float*)&x4;
            #pragma unroll
            for (int i = 0; i < 4; i++)
                #pragma unroll
                for (int j = 0; j < 4; j++) acc[i][j] += aa[i] * xx[j];
        }
        __syncthreads();
    }
    #pragma unroll
    for (int i = 0; i < 4; i++) {
        int n = n0 + tn * 4 + i;
        if (n < NN) {
            float4 v = make_float4(acc[i][0], acc[i][1], acc[i][2], acc[i][3]);
            *(float4*)&dstp[(size_t)n * 2048 + col0 + tc * 4] = v;
        }
    }
}

// ---------------- x-part preact precompute, layer 0 (K=2) ----------------
__global__ __launch_bounds__(256) void k_xprep0() {
    int n = blockIdx.x, t = blockIdx.y, tid = threadIdx.x;
    __shared__ float xv[32], ax[32];
    if (tid < 32) {
        xv[tid] = g_buf[S_SRC + ((size_t)tid * TT + t) * NN + n];
        ax[tid] = g_buf[OFF_AX0 + ((size_t)t * NN + n) * 32 + tid];
    }
    __syncthreads();
    size_t pbase = ((size_t)t * NN + n) * 32;
    for (int idx = tid; idx < 4096; idx += 256) {
        int b = idx >> 7, o = idx & 127;
        g_buf[OFF_GXP + (pbase + b) * 128 + o] =
            g_buf[BG0 + (size_t)n * 128 + o]
          + g_buf[G0X + ((size_t)n * 2 + 0) * 128 + o] * xv[b]
          + g_buf[G0X + ((size_t)n * 2 + 1) * 128 + o] * ax[b];
    }
    for (int idx = tid; idx < 2048; idx += 256) {
        int b = idx >> 6, o = idx & 63;
        g_buf[OFF_UXP + (pbase + b) * 64 + o] =
            g_buf[BU0 + (size_t)n * 64 + o]
          + g_buf[U0X + ((size_t)n * 2 + 0) * 64 + o] * xv[b]
          + g_buf[U0X + ((size_t)n * 2 + 1) * 64 + o] * ax[b];
    }
}

// ---------------- x-part preact precompute, layer 1 (K=128, t-parallel GEMM) ----------------
__global__ __launch_bounds__(256, 2) void k_xprep1() {
    __shared__ float smem[12544];
    float* xh = smem;            // [32][136]
    float* Wl = smem + 4352;     // [64][128]
    int n = blockIdx.x, t = blockIdx.y, tid = threadIdx.x;
    size_t pbase = ((size_t)t * NN + n) * 32;
    for (int idx = tid; idx < 4096; idx += 256) {
        int bl = idx >> 7, c = idx & 127;
        float v = (c < 64) ? g_buf[OFF_OUT0 + (pbase + bl) * 64 + c]
                           : g_buf[OFF_AX1 + (pbase + bl) * 64 + (c - 64)];
        xh[bl * 136 + c] = v;
    }
    int o = tid & 63, bl0 = (tid >> 6) * 8;
    float accz[8], accr[8];
    #pragma unroll
    for (int j = 0; j < 8; j++) {
        accz[j] = g_buf[BG1 + (size_t)n * 128 + o];
        accr[j] = g_buf[BG1 + (size_t)n * 128 + o + 64];
    }
    for (int ch = 0; ch < 2; ch++) {
        __syncthreads();
        const float4* wsrc = (const float4*)&g_buf[G1X + (size_t)n * 16384 + ch * 8192];
        float4* wdst = (float4*)Wl;
        for (int idx = tid; idx < 2048; idx += 256) wdst[idx] = wsrc[idx];
        __syncthreads();
        #pragma unroll 4
        for (int kq = 0; kq < 64; kq += 4) {
            float4 xv[8];
            #pragma unroll
            for (int j = 0; j < 8; j++) xv[j] = *(const float4*)&xh[(bl0 + j) * 136 + ch * 64 + kq];
            #pragma unroll
            for (int q = 0; q < 4; q++) {
                float w0 = Wl[(kq + q) * 128 + o];
                float w1 = Wl[(kq + q) * 128 + o + 64];
                #pragma unroll
                for (int j = 0; j < 8; j++) {
                    float xx = ((const float*)&xv[j])[q];
                    accz[j] += xx * w0;
                    accr[j] += xx * w1;
                }
            }
        }
    }
    #pragma unroll
    for (int j = 0; j < 8; j++) {
        g_buf[OFF_GXP + (pbase + bl0 + j) * 128 + o]      = accz[j];
        g_buf[OFF_GXP + (pbase + bl0 + j) * 128 + o + 64] = accr[j];
    }
    float acc[8];
    #pragma unroll
    for (int j = 0; j < 8; j++) acc[j] = g_buf[BU1 + (size_t)n * 64 + o];
    for (int ch = 0; ch < 2; ch++) {
        __syncthreads();
        const float4* wsrc = (const float4*)&g_buf[U1X + (size_t)n * 8192 + ch * 4096];
        float4* wdst = (float4*)Wl;
        for (int idx = tid; idx < 1024; idx += 256) wdst[idx] = wsrc[idx];
        __syncthreads();
        #pragma unroll 4
        for (int kq = 0; kq < 64; kq += 4) {
            float4 xv[8];
            #pragma unroll
            for (int j = 0; j < 8; j++) xv[j] = *(const float4*)&xh[(bl0 + j) * 136 + ch * 64 + kq];
            #pragma unroll
            for (int q = 0; q < 4; q++) {
                float w = Wl[(kq + q) * 64 + o];
                #pragma unroll
                for (int j = 0; j < 8; j++) acc[j] += ((const float*)&xv[j])[q] * w;
            }
        }
    }
    #pragma unroll
    for (int j = 0; j < 8; j++) g_buf[OFF_UXP + (pbase + bl0 + j) * 64 + o] = acc[j];
}

// ---------------- persistent scan phases ----------------
__device__ void phase_agg(float* smem, size_t srcOff) {
    int bid = blockIdx.x;
    if (bid < 320) {
        float* As = smem;          // 32*33
        float* Xs = smem + 1056;   // 32*64
        int n0 = (bid >> 5) * 32, col0 = (bid & 31) * 64;
        int tid = threadIdx.x;
        int tn2 = (tid >> 4) * 2, tc4 = (tid & 15) * 4;
        float acc[2][4];
        #pragma unroll
        for (int i = 0; i < 2; i++)
            #pragma unroll
            for (int j = 0; j < 4; j++) acc[i][j] = 0.f;
        for (int m0 = 0; m0 < NN; m0 += 32) {
            for (int idx = tid; idx < 1024; idx += 256) {
                int i = idx >> 5, k = idx & 31;
                int n = n0 + i, m = m0 + k;
                As[k * 33 + i] = (n < NN && m < NN) ? g_buf[OFF_A + (size_t)n * NN + m] : 0.f;
            }
            for (int idx = tid; idx < 2048; idx += 256) {
                int k = idx >> 6, c = idx & 63;
                int m = m0 + k;
                Xs[k * 64 + c] = (m < NN) ? g_buf[srcOff + (size_t)m * 2048 + col0 + c] : 0.f;
            }
            __syncthreads();
            #pragma unroll 8
            for (int k = 0; k < 32; k++) {
                float a0 = As[k * 33 + tn2];
                float a1 = As[k * 33 + tn2 + 1];
                float4 x4 = *(const float4*)&Xs[k * 64 + tc4];
                const float* xx = (const float*)&x4;
                #pragma unroll
                for (int j = 0; j < 4; j++) { acc[0][j] += a0 * xx[j]; acc[1][j] += a1 * xx[j]; }
            }
            __syncthreads();
        }
        #pragma unroll
        for (int i = 0; i < 2; i++) {
            int n = n0 + tn2 + i;
            if (n < NN) {
                float4 v = make_float4(acc[i][0], acc[i][1], acc[i][2], acc[i][3]);
                *(float4*)&g_buf[OFF_AGG + (size_t)n * 2048 + col0 + tc4] = v;
            }
        }
    }
}

__device__ void phase_gate(float* smem, int t, size_t GhOff) {
    int n = blockIdx.x;
    if (n < NN) {
        float* xh = smem;           // [32][136]
        float* Wl = smem + 4352;    // [64][128]
        int tid = threadIdx.x;
        for (int idx = tid; idx < 4096; idx += 256) {
            int bl = idx >> 7, c = idx & 127;
            float v = (c < 64) ? g_buf[OFF_H + (size_t)n * 2048 + bl * 64 + c]
                               : g_buf[OFF_AGG + (size_t)n * 2048 + bl * 64 + (c - 64)];
            xh[bl * 136 + c] = v;
        }
        int o = tid & 63, bl0 = (tid >> 6) * 8;
        size_t pbase = ((size_t)t * NN + n) * 32;
        float accz[8], accr[8];
        #pragma unroll
        for (int j = 0; j < 8; j++) {
            accz[j] = g_buf[OFF_GXP + (pbase + bl0 + j) * 128 + o];
            accr[j] = g_buf[OFF_GXP + (pbase + bl0 + j) * 128 + o + 64];
        }
        for (int ch = 0; ch < 2; ch++) {
            __syncthreads();
            const float4* wsrc = (const float4*)&g_buf[GhOff + (size_t)n * 16384 + ch * 8192];
            float4* wdst = (float4*)Wl;
            for (int idx = tid; idx < 2048; idx += 256) wdst[idx] = wsrc[idx];
            __syncthreads();
            #pragma unroll 4
            for (int kq = 0; kq < 64; kq += 4) {
                float4 xv[8];
                #pragma unroll
                for (int j = 0; j < 8; j++) xv[j] = *(const float4*)&xh[(bl0 + j) * 136 + ch * 64 + kq];
                #pragma unroll
                for (int q = 0; q < 4; q++) {
                    float w0 = Wl[(kq + q) * 128 + o];
                    float w1 = Wl[(kq + q) * 128 + o + 64];
                    #pragma unroll
                    for (int j = 0; j < 8; j++) {
                        float xx = ((const float*)&xv[j])[q];
                        accz[j] += xx * w0;
                        accr[j] += xx * w1;
                    }
                }
            }
        }
        #pragma unroll
        for (int j = 0; j < 8; j++) {
            int b = bl0 + j;
            float z = 1.f / (1.f + expf(-accz[j]));
            float r = 1.f / (1.f + expf(-accr[j]));
            float hv = xh[b * 136 + o];
            g_buf[OFF_ZH + (size_t)n * 2048 + b * 64 + o] = z * hv;
            g_buf[OFF_R  + (size_t)n * 2048 + b * 64 + o] = r;
        }
    }
}

template<bool WOUT>
__device__ void phase_upd(float* smem, int t, size_t UhOff) {
    int n = blockIdx.x;
    if (n < NN) {
        float* xh = smem;
        float* Wl = smem + 4352;    // [64][64]
        int tid = threadIdx.x;
        for (int idx = tid; idx < 4096; idx += 256) {
            int bl = idx >> 7, c = idx & 127;
            float v = (c < 64) ? g_buf[OFF_ZH + (size_t)n * 2048 + bl * 64 + c]
                               : g_buf[OFF_AGG + (size_t)n * 2048 + bl * 64 + (c - 64)];
            xh[bl * 136 + c] = v;
        }
        int o = tid & 63, bl0 = (tid >> 6) * 8;
        size_t pbase = ((size_t)t * NN + n) * 32;
        float acc[8];
        #pragma unroll
        for (int j = 0; j < 8; j++) acc[j] = g_buf[OFF_UXP + (pbase + bl0 + j) * 64 + o];
        for (int ch = 0; ch < 2; ch++) {
            __syncthreads();
            const float4* wsrc = (const float4*)&g_buf[UhOff + (size_t)n * 8192 + ch * 4096];
            float4* wdst = (float4*)Wl;
            for (int idx = tid; idx < 1024; idx += 256) wdst[idx] = wsrc[idx];
            __syncthreads();
            #pragma unroll 4
            for (int kq = 0; kq < 64; kq += 4) {
                float4 xv[8];
                #pragma unroll
                for (int j = 0; j < 8; j++) xv[j] = *(const float4*)&xh[(bl0 + j) * 136 + ch * 64 + kq];
                #pragma unroll
                for (int q = 0; q < 4; q++) {
                    float w = Wl[(kq + q) * 64 + o];
                    #pragma unroll
                    for (int j = 0; j < 8; j++) acc[j] += ((const float*)&xv[j])[q] * w;
                }
            }
        }
        #pragma unroll
        for (int j = 0; j < 8; j++) {
            int b = bl0 + j;
            size_t base = (size_t)n * 2048 + b * 64 + o;
            float hc = tanhf(acc[j]);
            float r = g_buf[OFF_R + base];
            float hold = g_buf[OFF_H + base];
            float hn = r * hold + (1.f - r) * hc;
            g_buf[OFF_H + base] = hn;
            if constexpr (WOUT) g_buf[OFF_OUT0 + (pbase + b) * 64 + o] = hn;
        }
    }
}

// ---------------- persistent GRU layer scan: 12 steps, 4 grid-barriers/step ----------------
template<bool WOUT>
__global__ __launch_bounds__(256, 2) void k_scan(size_t GhOff, size_t UhOff) {
    __shared__ float smem[12544];   // 50 KB: 2 blocks/CU residency guaranteed
    #pragma unroll 1
    for (int t = 0; t < TT; t++) {
        phase_agg(smem, OFF_H);          gridbar();
        phase_gate(smem, t, GhOff);      gridbar();
        phase_agg(smem, OFF_ZH);         gridbar();
        phase_upd<WOUT>(smem, t, UhOff); gridbar();
    }
}

// ---------------- fused attention (t=T-1 only) + LN1; 4 (b,n) per block ----------------
__global__ __launch_bounds__(256) void k_attn() {
    int wid = threadIdx.x >> 6;
    int lane = threadIdx.x & 63;
    int g = blockIdx.x * 4 + wid;
    int b = g / NN, n = g - b * NN;
    __shared__ float x[4][TT][HH], kk[4][TT][HH], vv[4][TT][HH];
    __shared__ float q[4][HH], o1[4][HH], sc[4][HEADS][TT], aw[4][HEADS][TT];
    float mw = g_buf[S_MLW + lane];
    float mb = g_buf[S_MLB + lane];
    #pragma unroll
    for (int tt = 0; tt < TT; tt++) {
        float s = g_buf[S_SRC + ((size_t)b * TT + tt) * NN + n];
        x[wid][tt][lane] = s * mw + mb + g_buf[OFF_PE + tt * HH + lane];
    }
    __syncthreads();
    float ka[TT], va[TT];
    #pragma unroll
    for (int tt = 0; tt < TT; tt++) { ka[tt] = g_buf[S_BK + lane]; va[tt] = g_buf[S_BV + lane]; }
    float qa = g_buf[S_BQ + lane];
    for (int i = 0; i < HH; i++) {
        float wkv = g_buf[S_WK + i * HH + lane];
        float wvv = g_buf[S_WV + i * HH + lane];
        qa += x[wid][TT - 1][i] * g_buf[S_WQ + i * HH + lane];
        #pragma unroll
        for (int tt = 0; tt < TT; tt++) {
            float xv = x[wid][tt][i];
            ka[tt] += xv * wkv;
            va[tt] += xv * wvv;
        }
    }
    #pragma unroll
    for (int tt = 0; tt < TT; tt++) { kk[wid][tt][lane] = ka[tt]; vv[wid][tt][lane] = va[tt]; }
    q[wid][lane] = qa;
    __syncthreads();
    if (lane < HEADS * TT) {
        int head = lane / TT, ts = lane - head * TT;
        float s = 0.f;
        #pragma unroll
        for (int d = 0; d < HD; d++) s += q[wid][head * HD + d] * kk[wid][ts][head * HD + d];
        sc[wid][head][ts] = s * 0.25f;
    }
    __syncthreads();
    if (lane < HEADS * TT) {
        int head = lane / TT, ts = lane - head * TT;
        float mx = -1e30f;
        #pragma unroll
        for (int j = 0; j < TT; j++) mx = fmaxf(mx, sc[wid][head][j]);
        float sm = 0.f;
        #pragma unroll
        for (int j = 0; j < TT; j++) sm += expf(sc[wid][head][j] - mx);
        aw[wid][head][ts] = expf(sc[wid][head][ts] - mx) / sm;
    }
    __syncthreads();
    int head = lane >> 4;
    float oa = 0.f;
    #pragma unroll
    for (int tt = 0; tt < TT; tt++) oa += aw[wid][head][tt] * vv[wid][tt][lane];
    o1[wid][lane] = oa;
    __syncthreads();
    float acc = g_buf[S_BO + lane];
    for (int i = 0; i < HH; i++) acc += o1[wid][i] * g_buf[S_WO + i * HH + lane];
    float res = x[wid][TT - 1][lane] + acc;
    float mean = wave_sum(res) * (1.f / 64.f);
    float dv = res - mean;
    float var = wave_sum(dv * dv) * (1.f / 64.f);
    float ln = dv * rsqrtf(var + 1e-5f) * g_buf[S_L1G + lane] + g_buf[S_L1B + lane];
    g_buf[OFF_OLN + ((size_t)b * NN + n) * HH + lane] = ln;
}

// ---------------- FFN + LN2; 8 tokens per block ----------------
__global__ __launch_bounds__(256) void k_ffn() {
    int tok0 = blockIdx.x * 8;
    int tid = threadIdx.x;
    __shared__ float ox[8][HH];
    __shared__ float hid[8][1024];
    for (int idx = tid; idx < 8 * HH; idx += 256) {
        int tk = idx >> 6, hh = idx & 63;
        ox[tk][hh] = g_buf[OFF_OLN + (size_t)(tok0 + tk) * HH + hh];
    }
    __syncthreads();
    #pragma unroll
    for (int p = 0; p < 4; p++) {
        int j = tid + 256 * p;
        float bj = g_buf[S_FB1 + j];
        float a[8];
        #pragma unroll
        for (int tk = 0; tk < 8; tk++) a[tk] = bj;
        for (int i = 0; i < HH; i++) {
            float w = g_buf[S_FW1 + (size_t)i * 1024 + j];
            #pragma unroll
            for (int tk = 0; tk < 8; tk++) a[tk] += ox[tk][i] * w;
        }
        #pragma unroll
        for (int tk = 0; tk < 8; tk++) hid[tk][j] = fmaxf(a[tk], 0.f);
    }
    __syncthreads();
    int tk = tid >> 6, hh = tid & 63;
    float acc0 = g_buf[S_FB2 + hh], acc1 = acc0;
    for (int j = 0; j < 1024; j++) {
        float w = g_buf[S_FW2 + (size_t)j * HH + hh];
        acc0 += hid[tk][j] * w;
        acc1 += hid[tk + 4][j] * w;
    }
    #pragma unroll
    for (int ph = 0; ph < 2; ph++) {
        int tkk = tk + 4 * ph;
        float res = ox[tkk][hh] + (ph ? acc1 : acc0);
        float mean = wave_sum(res) * (1.f / 64.f);
        float dv = res - mean;
        float var = wave_sum(dv * dv) * (1.f / 64.f);
        float ln = dv * rsqrtf(var + 1e-5f) * g_buf[S_L2G + hh] + g_buf[S_L2B + hh];
        g_buf[OFF_O2 + (size_t)(tok0 + tkk) * HH + hh] = ln;
    }
}

// ---------------- final combine + horizon conv ----------------
__global__ void k_final(void* out) {
    int n = blockIdx.x, b = blockIdx.y;
    int h = threadIdx.x;
    __shared__ float comb[HH];
    comb[h] = g_buf[OFF_H + ((size_t)n * 32 + b) * 64 + h] * g_buf[S_WS + n * HH + h]
            + g_buf[OFF_O2 + ((size_t)b * NN + n) * 64 + h] * g_buf[S_WT + n * HH + h];
    __syncthreads();
    if (h < HORIZON) {
        float acc = g_buf[S_CB + h];
        #pragma unroll
        for (int i = 0; i < HH; i++) acc += comb[i] * g_buf[S_CW + h * HH + i];
        size_t oi = ((size_t)b * HORIZON + h) * NN + n;
        if (g_flag) ((bf16*)out)[oi] = __float2bfloat16(acc);
        else        ((float*)out)[oi] = acc;
    }
}

extern "C" void kernel_launch(void* const* d_in, const int* in_sizes, int n_in,
                              void* d_out, int out_size, void* d_ws, size_t ws_size,
                              hipStream_t stream) {
    PtrPack pk;
    for (int i = 0; i < 32; i++) pk.p[i] = d_in[i];

    k_detect<<<1, 64, 0, stream>>>(d_in[1]);
    k_ingest<<<4133, 256, 0, stream>>>(pk);
    k_adj<<<NN, 512, 0, stream>>>();
    k_nodew_all<<<89337, 256, 0, stream>>>();
    k_pe<<<1, 768, 0, stream>>>();
    k_ax0<<<dim3(39, 12), 256, 0, stream>>>();
    k_xprep0<<<dim3(NN, 12), 256, 0, stream>>>();

    // ---- GRU layer 0: one persistent kernel, 12 steps ----
    k_zero<<<2456, 256, 0, stream>>>(OFF_H, 628736);
    k_scan<true><<<NBLK, 256, 0, stream>>>(G0H, U0H);

    // ---- layer-1 x-part precompute (t-parallel) ----
    k_aggmat<<<dim3(5, 32, 12), 256, 0, stream>>>(OFF_OUT0, OFF_AX1, 628736, 628736);
    k_xprep1<<<dim3(NN, 12), 256, 0, stream>>>();

    // ---- GRU layer 1 ----
    k_zero<<<2456, 256, 0, stream>>>(OFF_H, 628736);
    k_scan<false><<<NBLK, 256, 0, stream>>>(G1H, U1H);

    // ---- transformer branch ----
    k_attn<<<2456, 256, 0, stream>>>();
    k_ffn<<<1228, 256, 0, stream>>>();
    // ---- combine + conv ----
    k_final<<<dim3(NN, BB), 64, 0, stream>>>(d_out);
}

// Round 8
// 4107.979 us; speedup vs baseline: 5.3723x; 5.3723x over previous
//
#include <hip/hip_runtime.h>
#include <hip/hip_bf16.h>

typedef __hip_bfloat16 bf16;

constexpr int NN = 307, TT = 12, BB = 32, HH = 64, EE = 10, HEADS = 4, HD = 16, HORIZON = 12;

// ---------------- staged fp32 input offsets ----------------
constexpr int S_SRC = 0,       S_EMB = 117888,  S_GW0 = 120958,  S_GB0 = 287358,
              S_UW0 = 288638,  S_UB0 = 371838,  S_GW1 = 372478,  S_GB1 = 700158,
              S_UW1 = 701438,  S_UB1 = 865278,  S_MLW = 865918,  S_MLB = 865982,
              S_WQ  = 866046,  S_BQ  = 870142,  S_WK  = 870206,  S_BK  = 874302,
              S_WV  = 874366,  S_BV  = 878462,  S_WO  = 878526,  S_BO  = 882622,
              S_FW1 = 882686,  S_FB1 = 948222,  S_FW2 = 949246,  S_FB2 = 1014782,
              S_L1G = 1014846, S_L1B = 1014910, S_L2G = 1014974, S_L2B = 1015038,
              S_WS  = 1015102, S_WT  = 1034750, S_CW  = 1054398, S_CB  = 1055166;

// ---------------- fp32 work regions ----------------
constexpr size_t OFF_A    = 1055178;   // 307*307
constexpr size_t OFF_OUT0 = 1149427;   // [t][n][b][c] 12*307*2048
constexpr size_t OFF_H    = 8694259;   // [n][b][c] 307*2048
constexpr size_t OFF_ZH   = 9322995;
constexpr size_t OFF_R    = 9951731;
constexpr size_t OFF_AX0  = 11209203;  // [t][n][b] 12*307*32
constexpr size_t OFF_AX1  = 11327091;  // [t][n][b][c] 12*307*2048
constexpr size_t OFF_PE   = 18871923;  // 12*64
constexpr size_t OFF_OLN  = 18872691;
constexpr size_t OFF_O2   = 19501427;
constexpr size_t OFF_WB   = 20130164;  // fp32 reordered per-node GRU weights

// Reordered weight blocks (fp32; bf16 storage fails: scan amplifies to 0.19 absmax — r3)
constexpr size_t G0X = OFF_WB +        0;  // 307*2*128
constexpr size_t G0H = OFF_WB +    78592;  // 307*128*128
constexpr size_t BG0 = OFF_WB +  5108480;  // 307*128
constexpr size_t U0X = OFF_WB +  5147776;  // 307*2*64
constexpr size_t U0H = OFF_WB +  5187072;  // 307*128*64
constexpr size_t BU0 = OFF_WB +  7702016;  // 307*64
constexpr size_t G1X = OFF_WB +  7721664;  // 307*128*128
constexpr size_t G1H = OFF_WB + 12751552;  // 307*128*128
constexpr size_t BG1 = OFF_WB + 17781440;  // 307*128
constexpr size_t U1X = OFF_WB + 17820736;  // 307*128*64
constexpr size_t U1H = OFF_WB + 20335680;  // 307*128*64
constexpr size_t BU1 = OFF_WB + 22850624;  // 307*64
constexpr size_t OFF_GXP = OFF_WB + 22870272;       // [t][n][b][128] preact x-part (bias folded)
constexpr size_t OFF_UXP = OFF_GXP + 15089664;      // [t][n][b][64]
constexpr size_t G_TOTAL = OFF_UXP + 7544832 + 4096;

// r7->r8: persistent k_scan with agent-scope gridbar measured ~200us/barrier
// (acquire invalidates per-XCD L2 -> 30MB/step weight refetch, FETCH 360+MB,
// VALUBusy 2%). Reverted to stream dispatches; agg fused into gate/upd so the
// serial chain is 2 dispatches/step (48 total) instead of 4.

__device__ float g_buf[G_TOTAL];
__device__ int g_flag;   // 1 = inputs are bf16, 0 = fp32

__device__ __forceinline__ float wave_sum(float v) {
    #pragma unroll
    for (int off = 32; off > 0; off >>= 1) v += __shfl_xor(v, off, 64);
    return v;
}

// ---------------- dtype detection ----------------
__global__ void k_detect(const void* emb_raw) {
    const bf16* p = (const bf16*)emb_raw;
    int lane = threadIdx.x;
    float v = __bfloat162float(p[lane]);
    bool plaus = (v == v) && (fabsf(v) <= 1e4f) && (v == 0.f || fabsf(v) >= 1e-4f);
    float c = wave_sum(plaus ? 1.f : 0.f);
    if (lane == 0) g_flag = (c >= 52.f) ? 1 : 0;
}

// ---------------- ingest all inputs as fp32 ----------------
struct PtrPack { const void* p[32]; };
__device__ const int D_CNT[32] = {117888,3070,166400,1280,83200,640,327680,1280,163840,640,
                                  64,64,4096,64,4096,64,4096,64,4096,64,
                                  65536,1024,65536,64,64,64,64,64,19648,19648,768,12};
__device__ const int D_OFF[32] = {S_SRC,S_EMB,S_GW0,S_GB0,S_UW0,S_UB0,S_GW1,S_GB1,S_UW1,S_UB1,
                                  S_MLW,S_MLB,S_WQ,S_BQ,S_WK,S_BK,S_WV,S_BV,S_WO,S_BO,
                                  S_FW1,S_FB1,S_FW2,S_FB2,S_L1G,S_L1B,S_L2G,S_L2B,S_WS,S_WT,S_CW,S_CB};
__device__ const int D_CHK[33] = {0,461,473,1123,1128,1453,1456,2736,2741,3381,3384,3385,3386,
                                  3402,3403,3419,3420,3436,3437,3453,3454,3710,3714,3970,3971,
                                  3972,3973,3974,3975,4052,4129,4132,4133};

__global__ void k_ingest(PtrPack pk) {
    int bid = blockIdx.x;
    int s = 0;
    while (s < 31 && bid >= D_CHK[s + 1]) s++;
    int i = (bid - D_CHK[s]) * 256 + threadIdx.x;
    if (i >= D_CNT[s]) return;
    float v;
    if (g_flag) v = __bfloat162float(((const bf16*)pk.p[s])[i]);
    else        v = ((const float*)pk.p[s])[i];
    g_buf[(size_t)D_OFF[s] + i] = v;
}

// ---------------- adjacency ----------------
__global__ void k_adj() {
    int n = blockIdx.x;
    int tid = threadIdx.x;            // 512
    __shared__ float en[EE];
    __shared__ float red[512];
    if (tid < EE) en[tid] = g_buf[S_EMB + n * EE + tid];
    __syncthreads();
    bool act = tid < NN;
    float d = 0.f;
    if (act) {
        #pragma unroll
        for (int e = 0; e < EE; e++) d += en[e] * g_buf[S_EMB + tid * EE + e];
        d = fmaxf(d, 0.f);
    }
    red[tid] = act ? d : -1e30f;
    __syncthreads();
    for (int s = 256; s > 0; s >>= 1) { if (tid < s) red[tid] = fmaxf(red[tid], red[tid + s]); __syncthreads(); }
    float mx = red[0];
    __syncthreads();
    float ex = act ? expf(d - mx) : 0.f;
    red[tid] = ex;
    __syncthreads();
    for (int s = 256; s > 0; s >>= 1) { if (tid < s) red[tid] += red[tid + s]; __syncthreads(); }
    float inv = 1.f / red[0];
    if (act) g_buf[OFF_A + (size_t)n * NN + tid] = ex * inv;
}

// ---------------- per-node GRU weights -> fp32, reordered into Wx/Wh blocks ----------------
__device__ const unsigned SEGC[9] = {0u,5108480u,5147776u,7702016u,7721664u,17781440u,17820736u,22850624u,22870272u};
__device__ const int SEGJ[8]      = {16640,128,8320,64,32768,128,16384,64};
__device__ const int SEGS[8]      = {S_GW0,S_GB0,S_UW0,S_UB0,S_GW1,S_GB1,S_UW1,S_UB1};

__global__ void k_nodew_all() {
    unsigned idx = blockIdx.x * 256u + threadIdx.x;
    if (idx >= 22870272u) return;
    int s = 0;
    while (s < 7 && idx >= SEGC[s + 1]) s++;
    unsigned rem = idx - SEGC[s];
    unsigned J = (unsigned)SEGJ[s];
    unsigned n = rem / J;
    unsigned j = rem - n * J;
    float acc = 0.f;
    const float* eb = g_buf + S_EMB + n * EE;
    const float* w  = g_buf + SEGS[s];
    #pragma unroll
    for (int e = 0; e < EE; e++) acc += eb[e] * w[(size_t)e * J + j];
    size_t dst;
    if (s == 0) {        // gw0: j = (k*65+i)*128+o
        unsigned o = j & 127, kk = j >> 7, k = kk / 65, i = kk % 65;
        dst = (i == 0) ? G0X + ((size_t)n * 2 + k) * 128 + o
                       : G0H + ((size_t)n * 128 + k * 64 + (i - 1)) * 128 + o;
    } else if (s == 1) { dst = BG0 + (size_t)n * 128 + j;
    } else if (s == 2) { // uw0: j = (k*65+i)*64+o
        unsigned o = j & 63, kk = j >> 6, k = kk / 65, i = kk % 65;
        dst = (i == 0) ? U0X + ((size_t)n * 2 + k) * 64 + o
                       : U0H + ((size_t)n * 128 + k * 64 + (i - 1)) * 64 + o;
    } else if (s == 3) { dst = BU0 + (size_t)n * 64 + j;
    } else if (s == 4) { // gw1: j = (k*128+i)*128+o
        unsigned o = j & 127, kk = j >> 7, k = kk >> 7, i = kk & 127;
        dst = (i < 64) ? G1X + ((size_t)n * 128 + k * 64 + i) * 128 + o
                       : G1H + ((size_t)n * 128 + k * 64 + (i - 64)) * 128 + o;
    } else if (s == 5) { dst = BG1 + (size_t)n * 128 + j;
    } else if (s == 6) { // uw1: j = (k*128+i)*64+o
        unsigned o = j & 63, kk = j >> 6, k = kk >> 7, i = kk & 127;
        dst = (i < 64) ? U1X + ((size_t)n * 128 + k * 64 + i) * 64 + o
                       : U1H + ((size_t)n * 128 + k * 64 + (i - 64)) * 64 + o;
    } else {             dst = BU1 + (size_t)n * 64 + j; }
    g_buf[dst] = acc;
}

// ---------------- positional embedding ----------------
__global__ void k_pe() {
    int tid = threadIdx.x;            // 768
    int t = tid >> 6, h = tid & 63;
    float ex = (float)(h & ~1) / 64.f;
    float ang = (float)t * powf(10000.f, -ex);
    g_buf[OFF_PE + tid] = (h & 1) ? cosf(ang) : sinf(ang);
}

__global__ void k_zero(size_t off, int cnt) {
    int i = blockIdx.x * 256 + threadIdx.x;
    if (i < cnt) g_buf[off + i] = 0.f;
}

// ---------------- AX0[t][n][b] = sum_m A[n,m] * src[b,t,m] ----------------
__global__ __launch_bounds__(256) void k_ax0() {
    int t = blockIdx.y;
    int n0 = blockIdx.x * 8;
    int b = threadIdx.x & 31, nl = threadIdx.x >> 5;
    __shared__ float As[8][68];
    __shared__ float xs[32][65];
    float acc = 0.f;
    for (int m0 = 0; m0 < NN; m0 += 64) {
        int jend = min(64, NN - m0);
        for (int idx = threadIdx.x; idx < 8 * 64; idx += 256) {
            int i = idx >> 6, jj = idx & 63;
            int n = n0 + i, m = m0 + jj;
            As[i][jj] = (n < NN && m < NN) ? g_buf[OFF_A + (size_t)n * NN + m] : 0.f;
        }
        for (int idx = threadIdx.x; idx < 32 * 64; idx += 256) {
            int bb = idx >> 6, jj = idx & 63;
            int m = m0 + jj;
            xs[bb][jj] = (m < NN) ? g_buf[S_SRC + ((size_t)bb * TT + t) * NN + m] : 0.f;
        }
        __syncthreads();
        for (int jj = 0; jj < jend; jj++) acc += As[nl][jj] * xs[b][jj];
        __syncthreads();
    }
    int n = n0 + nl;
    if (n < NN) g_buf[OFF_AX0 + ((size_t)t * NN + n) * 32 + b] = acc;
}

// ---------------- standalone agg GEMM (used for AX1, z=12 parallel) ----------------
__global__ __launch_bounds__(256) void k_aggmat(size_t srcOff, size_t dstOff, size_t srcTS, size_t dstTS) {
    int z = blockIdx.z;
    const float* __restrict__ srcp = g_buf + srcOff + (size_t)z * srcTS;
    float* __restrict__ dstp = g_buf + dstOff + (size_t)z * dstTS;
    int n0 = blockIdx.x * 64;
    int col0 = blockIdx.y * 64;
    int tid = threadIdx.x;
    int tn = tid >> 4, tc = tid & 15;
    __shared__ float As[32][68];
    __shared__ float Xs[32][64];
    float acc[4][4];
    #pragma unroll
    for (int i = 0; i < 4; i++)
        #pragma unroll
        for (int j = 0; j < 4; j++) acc[i][j] = 0.f;
    for (int k0 = 0; k0 < NN; k0 += 32) {
        for (int idx = tid; idx < 64 * 32; idx += 256) {
            int k = idx & 31, i = idx >> 5;
            int n = n0 + i, m = k0 + k;
            As[k][i] = (n < NN && m < NN) ? g_buf[OFF_A + (size_t)n * NN + m] : 0.f;
        }
        for (int idx = tid; idx < 32 * 64; idx += 256) {
            int c = idx & 63, k = idx >> 6;
            int m = k0 + k;
            Xs[k][c] = (m < NN) ? srcp[(size_t)m * 2048 + col0 + c] : 0.f;
        }
        __syncthreads();
        #pragma unroll
        for (int k = 0; k < 32; k++) {
            float4 a4 = *(const float4*)&As[k][tn * 4];
            float4 x4 = *(const float4*)&Xs[k][tc * 4];
            const float* aa = (const float*)&a4;
            const float* xx = (const float*)&x4;
            #pragma unroll
            for (int i = 0; i < 4; i++)
                #pragma unroll
                for (int j = 0; j < 4; j++) acc[i][j] += aa[i] * xx[j];
        }
        __syncthreads();
    }
    #pragma unroll
    for (int i = 0; i < 4; i++) {
        int n = n0 + tn * 4 + i;
        if (n < NN) {
            float4 v = make_float4(acc[i][0], acc[i][1], acc[i][2], acc[i][3]);
            *(float4*)&dstp[(size_t)n * 2048 + col0 + tc * 4] = v;
        }
    }
}

// ---------------- x-part preact precompute, layer 0 (K=2) ----------------
__global__ __launch_bounds__(256) void k_xprep0() {
    int n = blockIdx.x, t = blockIdx.y, tid = threadIdx.x;
    __shared__ float xv[32], ax[32];
    if (tid < 32) {
        xv[tid] = g_buf[S_SRC + ((size_t)tid * TT + t) * NN + n];
        ax[tid] = g_buf[OFF_AX0 + ((size_t)t * NN + n) * 32 + tid];
    }
    __syncthreads();
    size_t pbase = ((size_t)t * NN + n) * 32;
    for (int idx = tid; idx < 4096; idx += 256) {
        int b = idx >> 7, o = idx & 127;
        g_buf[OFF_GXP + (pbase + b) * 128 + o] =
            g_buf[BG0 + (size_t)n * 128 + o]
          + g_buf[G0X + ((size_t)n * 2 + 0) * 128 + o] * xv[b]
          + g_buf[G0X + ((size_t)n * 2 + 1) * 128 + o] * ax[b];
    }
    for (int idx = tid; idx < 2048; idx += 256) {
        int b = idx >> 6, o = idx & 63;
        g_buf[OFF_UXP + (pbase + b) * 64 + o] =
            g_buf[BU0 + (size_t)n * 64 + o]
          + g_buf[U0X + ((size_t)n * 2 + 0) * 64 + o] * xv[b]
          + g_buf[U0X + ((size_t)n * 2 + 1) * 64 + o] * ax[b];
    }
}

// ---------------- x-part preact precompute, layer 1 (K=128, t-parallel GEMM) ----------------
__global__ __launch_bounds__(256, 2) void k_xprep1() {
    __shared__ float smem[12544];
    float* xh = smem;            // [32][136]
    float* Wl = smem + 4352;     // [64][128]
    int n = blockIdx.x, t = blockIdx.y, tid = threadIdx.x;
    size_t pbase = ((size_t)t * NN + n) * 32;
    for (int idx = tid; idx < 4096; idx += 256) {
        int bl = idx >> 7, c = idx & 127;
        float v = (c < 64) ? g_buf[OFF_OUT0 + (pbase + bl) * 64 + c]
                           : g_buf[OFF_AX1 + (pbase + bl) * 64 + (c - 64)];
        xh[bl * 136 + c] = v;
    }
    int o = tid & 63, bl0 = (tid >> 6) * 8;
    float accz[8], accr[8];
    #pragma unroll
    for (int j = 0; j < 8; j++) {
        accz[j] = g_buf[BG1 + (size_t)n * 128 + o];
        accr[j] = g_buf[BG1 + (size_t)n * 128 + o + 64];
    }
    for (int ch = 0; ch < 2; ch++) {
        __syncthreads();
        const float4* wsrc = (const float4*)&g_buf[G1X + (size_t)n * 16384 + ch * 8192];
        float4* wdst = (float4*)Wl;
        for (int idx = tid; idx < 2048; idx += 256) wdst[idx] = wsrc[idx];
        __syncthreads();
        #pragma unroll 4
        for (int kq = 0; kq < 64; kq += 4) {
            float4 xv[8];
            #pragma unroll
            for (int j = 0; j < 8; j++) xv[j] = *(const float4*)&xh[(bl0 + j) * 136 + ch * 64 + kq];
            #pragma unroll
            for (int q = 0; q < 4; q++) {
                float w0 = Wl[(kq + q) * 128 + o];
                float w1 = Wl[(kq + q) * 128 + o + 64];
                #pragma unroll
                for (int j = 0; j < 8; j++) {
                    float xx = ((const float*)&xv[j])[q];
                    accz[j] += xx * w0;
                    accr[j] += xx * w1;
                }
            }
        }
    }
    #pragma unroll
    for (int j = 0; j < 8; j++) {
        g_buf[OFF_GXP + (pbase + bl0 + j) * 128 + o]      = accz[j];
        g_buf[OFF_GXP + (pbase + bl0 + j) * 128 + o + 64] = accr[j];
    }
    float acc[8];
    #pragma unroll
    for (int j = 0; j < 8; j++) acc[j] = g_buf[BU1 + (size_t)n * 64 + o];
    for (int ch = 0; ch < 2; ch++) {
        __syncthreads();
        const float4* wsrc = (const float4*)&g_buf[U1X + (size_t)n * 8192 + ch * 4096];
        float4* wdst = (float4*)Wl;
        for (int idx = tid; idx < 1024; idx += 256) wdst[idx] = wsrc[idx];
        __syncthreads();
        #pragma unroll 4
        for (int kq = 0; kq < 64; kq += 4) {
            float4 xv[8];
            #pragma unroll
            for (int j = 0; j < 8; j++) xv[j] = *(const float4*)&xh[(bl0 + j) * 136 + ch * 64 + kq];
            #pragma unroll
            for (int q = 0; q < 4; q++) {
                float w = Wl[(kq + q) * 64 + o];
                #pragma unroll
                for (int j = 0; j < 8; j++) acc[j] += ((const float*)&xv[j])[q] * w;
            }
        }
    }
    #pragma unroll
    for (int j = 0; j < 8; j++) g_buf[OFF_UXP + (pbase + bl0 + j) * 64 + o] = acc[j];
}

// ---------------- fused gate: own-agg (A[n,:]@H) + h-part GEMM + sigmoid ----------------
template<int L>
__global__ __launch_bounds__(256) void k_gateF(int t) {
    constexpr size_t GH = (L == 0) ? G0H : G1H;
    int n = blockIdx.x, tid = threadIdx.x;
    __shared__ float Arow[308];
    __shared__ float xh[32 * 136];   // [b][k]: k<64 = h, k>=64 = A@h
    __shared__ float Wl[64 * 128];
    for (int idx = tid; idx < NN; idx += 256) Arow[idx] = g_buf[OFF_A + (size_t)n * NN + idx];
    for (int idx = tid; idx < 2048; idx += 256) {
        int b = idx >> 6, c = idx & 63;
        xh[b * 136 + c] = g_buf[OFF_H + (size_t)n * 2048 + idx];
    }
    __syncthreads();
    // own aggregation rows: thread owns 8 flat (b,c) elements
    float ag[8];
    #pragma unroll
    for (int j = 0; j < 8; j++) ag[j] = 0.f;
    #pragma unroll 4
    for (int m = 0; m < NN; m++) {
        float a = Arow[m];
        float4 h0 = *(const float4*)&g_buf[OFF_H + (size_t)m * 2048 + tid * 8];
        float4 h1 = *(const float4*)&g_buf[OFF_H + (size_t)m * 2048 + tid * 8 + 4];
        ag[0] += a * h0.x; ag[1] += a * h0.y; ag[2] += a * h0.z; ag[3] += a * h0.w;
        ag[4] += a * h1.x; ag[5] += a * h1.y; ag[6] += a * h1.z; ag[7] += a * h1.w;
    }
    #pragma unroll
    for (int j = 0; j < 8; j++) {
        int flat = tid * 8 + j;
        xh[(flat >> 6) * 136 + 64 + (flat & 63)] = ag[j];
    }
    int o = tid & 63, bl0 = (tid >> 6) * 8;
    size_t pbase = ((size_t)t * NN + n) * 32;
    float accz[8], accr[8];
    #pragma unroll
    for (int j = 0; j < 8; j++) {
        accz[j] = g_buf[OFF_GXP + (pbase + bl0 + j) * 128 + o];
        accr[j] = g_buf[OFF_GXP + (pbase + bl0 + j) * 128 + o + 64];
    }
    for (int ch = 0; ch < 2; ch++) {
        __syncthreads();
        const float4* wsrc = (const float4*)&g_buf[GH + (size_t)n * 16384 + ch * 8192];
        float4* wdst = (float4*)Wl;
        for (int idx = tid; idx < 2048; idx += 256) wdst[idx] = wsrc[idx];
        __syncthreads();
        #pragma unroll 4
        for (int kq = 0; kq < 64; kq += 4) {
            float4 xv[8];
            #pragma unroll
            for (int j = 0; j < 8; j++) xv[j] = *(const float4*)&xh[(bl0 + j) * 136 + ch * 64 + kq];
            #pragma unroll
            for (int q = 0; q < 4; q++) {
                float w0 = Wl[(kq + q) * 128 + o];
                float w1 = Wl[(kq + q) * 128 + o + 64];
                #pragma unroll
                for (int j = 0; j < 8; j++) {
                    float xx = ((const float*)&xv[j])[q];
                    accz[j] += xx * w0;
                    accr[j] += xx * w1;
                }
            }
        }
    }
    #pragma unroll
    for (int j = 0; j < 8; j++) {
        int b = bl0 + j;
        float z = 1.f / (1.f + expf(-accz[j]));
        float r = 1.f / (1.f + expf(-accr[j]));
        float hv = xh[b * 136 + o];
        g_buf[OFF_ZH + (size_t)n * 2048 + b * 64 + o] = z * hv;
        g_buf[OFF_R  + (size_t)n * 2048 + b * 64 + o] = r;
    }
}

// ---------------- fused update: own-agg (A[n,:]@ZH) + h-part GEMM + tanh + h update ----------------
template<int L, bool WOUT>
__global__ __launch_bounds__(256) void k_updF(int t) {
    constexpr size_t UH = (L == 0) ? U0H : U1H;
    int n = blockIdx.x, tid = threadIdx.x;
    __shared__ float Arow[308];
    __shared__ float xh[32 * 136];   // [b][k]: k<64 = z*h, k>=64 = A@(z*h)
    __shared__ float Wl[64 * 64];
    for (int idx = tid; idx < NN; idx += 256) Arow[idx] = g_buf[OFF_A + (size_t)n * NN + idx];
    for (int idx = tid; idx < 2048; idx += 256) {
        int b = idx >> 6, c = idx & 63;
        xh[b * 136 + c] = g_buf[OFF_ZH + (size_t)n * 2048 + idx];
    }
    __syncthreads();
    float ag[8];
    #pragma unroll
    for (int j = 0; j < 8; j++) ag[j] = 0.f;
    #pragma unroll 4
    for (int m = 0; m < NN; m++) {
        float a = Arow[m];
        float4 h0 = *(const float4*)&g_buf[OFF_ZH + (size_t)m * 2048 + tid * 8];
        float4 h1 = *(const float4*)&g_buf[OFF_ZH + (size_t)m * 2048 + tid * 8 + 4];
        ag[0] += a * h0.x; ag[1] += a * h0.y; ag[2] += a * h0.z; ag[3] += a * h0.w;
        ag[4] += a * h1.x; ag[5] += a * h1.y; ag[6] += a * h1.z; ag[7] += a * h1.w;
    }
    #pragma unroll
    for (int j = 0; j < 8; j++) {
        int flat = tid * 8 + j;
        xh[(flat >> 6) * 136 + 64 + (flat & 63)] = ag[j];
    }
    int o = tid & 63, bl0 = (tid >> 6) * 8;
    size_t pbase = ((size_t)t * NN + n) * 32;
    float acc[8];
    #pragma unroll
    for (int j = 0; j < 8; j++) acc[j] = g_buf[OFF_UXP + (pbase + bl0 + j) * 64 + o];
    for (int ch = 0; ch < 2; ch++) {
        __syncthreads();
        const float4* wsrc = (const float4*)&g_buf[UH + (size_t)n * 8192 + ch * 4096];
        float4* wdst = (float4*)Wl;
        for (int idx = tid; idx < 1024; idx += 256) wdst[idx] = wsrc[idx];
        __syncthreads();
        #pragma unroll 4
        for (int kq = 0; kq < 64; kq += 4) {
            float4 xv[8];
            #pragma unroll
            for (int j = 0; j < 8; j++) xv[j] = *(const float4*)&xh[(bl0 + j) * 136 + ch * 64 + kq];
            #pragma unroll
            for (int q = 0; q < 4; q++) {
                float w = Wl[(kq + q) * 64 + o];
                #pragma unroll
                for (int j = 0; j < 8; j++) acc[j] += ((const float*)&xv[j])[q] * w;
            }
        }
    }
    #pragma unroll
    for (int j = 0; j < 8; j++) {
        int b = bl0 + j;
        size_t base = (size_t)n * 2048 + b * 64 + o;
        float hc = tanhf(acc[j]);
        float r = g_buf[OFF_R + base];
        float hold = g_buf[OFF_H + base];
        float hn = r * hold + (1.f - r) * hc;
        g_buf[OFF_H + base] = hn;
        if constexpr (WOUT) g_buf[OFF_OUT0 + (pbase + b) * 64 + o] = hn;
    }
}

// ---------------- fused attention (t=T-1 only) + LN1; 4 (b,n) per block ----------------
__global__ __launch_bounds__(256) void k_attn() {
    int wid = threadIdx.x >> 6;
    int lane = threadIdx.x & 63;
    int g = blockIdx.x * 4 + wid;
    int b = g / NN, n = g - b * NN;
    __shared__ float x[4][TT][HH], kk[4][TT][HH], vv[4][TT][HH];
    __shared__ float q[4][HH], o1[4][HH], sc[4][HEADS][TT], aw[4][HEADS][TT];
    float mw = g_buf[S_MLW + lane];
    float mb = g_buf[S_MLB + lane];
    #pragma unroll
    for (int tt = 0; tt < TT; tt++) {
        float s = g_buf[S_SRC + ((size_t)b * TT + tt) * NN + n];
        x[wid][tt][lane] = s * mw + mb + g_buf[OFF_PE + tt * HH + lane];
    }
    __syncthreads();
    float ka[TT], va[TT];
    #pragma unroll
    for (int tt = 0; tt < TT; tt++) { ka[tt] = g_buf[S_BK + lane]; va[tt] = g_buf[S_BV + lane]; }
    float qa = g_buf[S_BQ + lane];
    for (int i = 0; i < HH; i++) {
        float wkv = g_buf[S_WK + i * HH + lane];
        float wvv = g_buf[S_WV + i * HH + lane];
        qa += x[wid][TT - 1][i] * g_buf[S_WQ + i * HH + lane];
        #pragma unroll
        for (int tt = 0; tt < TT; tt++) {
            float xv = x[wid][tt][i];
            ka[tt] += xv * wkv;
            va[tt] += xv * wvv;
        }
    }
    #pragma unroll
    for (int tt = 0; tt < TT; tt++) { kk[wid][tt][lane] = ka[tt]; vv[wid][tt][lane] = va[tt]; }
    q[wid][lane] = qa;
    __syncthreads();
    if (lane < HEADS * TT) {
        int head = lane / TT, ts = lane - head * TT;
        float s = 0.f;
        #pragma unroll
        for (int d = 0; d < HD; d++) s += q[wid][head * HD + d] * kk[wid][ts][head * HD + d];
        sc[wid][head][ts] = s * 0.25f;
    }
    __syncthreads();
    if (lane < HEADS * TT) {
        int head = lane / TT, ts = lane - head * TT;
        float mx = -1e30f;
        #pragma unroll
        for (int j = 0; j < TT; j++) mx = fmaxf(mx, sc[wid][head][j]);
        float sm = 0.f;
        #pragma unroll
        for (int j = 0; j < TT; j++) sm += expf(sc[wid][head][j] - mx);
        aw[wid][head][ts] = expf(sc[wid][head][ts] - mx) / sm;
    }
    __syncthreads();
    int head = lane >> 4;
    float oa = 0.f;
    #pragma unroll
    for (int tt = 0; tt < TT; tt++) oa += aw[wid][head][tt] * vv[wid][tt][lane];
    o1[wid][lane] = oa;
    __syncthreads();
    float acc = g_buf[S_BO + lane];
    for (int i = 0; i < HH; i++) acc += o1[wid][i] * g_buf[S_WO + i * HH + lane];
    float res = x[wid][TT - 1][lane] + acc;
    float mean = wave_sum(res) * (1.f / 64.f);
    float dv = res - mean;
    float var = wave_sum(dv * dv) * (1.f / 64.f);
    float ln = dv * rsqrtf(var + 1e-5f) * g_buf[S_L1G + lane] + g_buf[S_L1B + lane];
    g_buf[OFF_OLN + ((size_t)b * NN + n) * HH + lane] = ln;
}

// ---------------- FFN + LN2; 8 tokens per block ----------------
__global__ __launch_bounds__(256) void k_ffn() {
    int tok0 = blockIdx.x * 8;
    int tid = threadIdx.x;
    __shared__ float ox[8][HH];
    __shared__ float hid[8][1024];
    for (int idx = tid; idx < 8 * HH; idx += 256) {
        int tk = idx >> 6, hh = idx & 63;
        ox[tk][hh] = g_buf[OFF_OLN + (size_t)(tok0 + tk) * HH + hh];
    }
    __syncthreads();
    #pragma unroll
    for (int p = 0; p < 4; p++) {
        int j = tid + 256 * p;
        float bj = g_buf[S_FB1 + j];
        float a[8];
        #pragma unroll
        for (int tk = 0; tk < 8; tk++) a[tk] = bj;
        for (int i = 0; i < HH; i++) {
            float w = g_buf[S_FW1 + (size_t)i * 1024 + j];
            #pragma unroll
            for (int tk = 0; tk < 8; tk++) a[tk] += ox[tk][i] * w;
        }
        #pragma unroll
        for (int tk = 0; tk < 8; tk++) hid[tk][j] = fmaxf(a[tk], 0.f);
    }
    __syncthreads();
    int tk = tid >> 6, hh = tid & 63;
    float acc0 = g_buf[S_FB2 + hh], acc1 = acc0;
    for (int j = 0; j < 1024; j++) {
        float w = g_buf[S_FW2 + (size_t)j * HH + hh];
        acc0 += hid[tk][j] * w;
        acc1 += hid[tk + 4][j] * w;
    }
    #pragma unroll
    for (int ph = 0; ph < 2; ph++) {
        int tkk = tk + 4 * ph;
        float res = ox[tkk][hh] + (ph ? acc1 : acc0);
        float mean = wave_sum(res) * (1.f / 64.f);
        float dv = res - mean;
        float var = wave_sum(dv * dv) * (1.f / 64.f);
        float ln = dv * rsqrtf(var + 1e-5f) * g_buf[S_L2G + hh] + g_buf[S_L2B + hh];
        g_buf[OFF_O2 + (size_t)(tok0 + tkk) * HH + hh] = ln;
    }
}

// ---------------- final combine + horizon conv ----------------
__global__ void k_final(void* out) {
    int n = blockIdx.x, b = blockIdx.y;
    int h = threadIdx.x;
    __shared__ float comb[HH];
    comb[h] = g_buf[OFF_H + ((size_t)n * 32 + b) * 64 + h] * g_buf[S_WS + n * HH + h]
            + g_buf[OFF_O2 + ((size_t)b * NN + n) * 64 + h] * g_buf[S_WT + n * HH + h];
    __syncthreads();
    if (h < HORIZON) {
        float acc = g_buf[S_CB + h];
        #pragma unroll
        for (int i = 0; i < HH; i++) acc += comb[i] * g_buf[S_CW + h * HH + i];
        size_t oi = ((size_t)b * HORIZON + h) * NN + n;
        if (g_flag) ((bf16*)out)[oi] = __float2bfloat16(acc);
        else        ((float*)out)[oi] = acc;
    }
}

extern "C" void kernel_launch(void* const* d_in, const int* in_sizes, int n_in,
                              void* d_out, int out_size, void* d_ws, size_t ws_size,
                              hipStream_t stream) {
    PtrPack pk;
    for (int i = 0; i < 32; i++) pk.p[i] = d_in[i];

    k_detect<<<1, 64, 0, stream>>>(d_in[1]);
    k_ingest<<<4133, 256, 0, stream>>>(pk);
    k_adj<<<NN, 512, 0, stream>>>();
    k_nodew_all<<<89337, 256, 0, stream>>>();
    k_pe<<<1, 768, 0, stream>>>();
    k_ax0<<<dim3(39, 12), 256, 0, stream>>>();
    k_xprep0<<<dim3(NN, 12), 256, 0, stream>>>();

    // ---- GRU layer 0: 2 fused dispatches per step ----
    k_zero<<<2456, 256, 0, stream>>>(OFF_H, 628736);
    for (int t = 0; t < TT; t++) {
        k_gateF<0><<<NN, 256, 0, stream>>>(t);
        k_updF<0, true><<<NN, 256, 0, stream>>>(t);
    }
    // ---- layer-1 x-part precompute (t-parallel) ----
    k_aggmat<<<dim3(5, 32, 12), 256, 0, stream>>>(OFF_OUT0, OFF_AX1, 628736, 628736);
    k_xprep1<<<dim3(NN, 12), 256, 0, stream>>>();
    // ---- GRU layer 1 ----
    k_zero<<<2456, 256, 0, stream>>>(OFF_H, 628736);
    for (int t = 0; t < TT; t++) {
        k_gateF<1><<<NN, 256, 0, stream>>>(t);
        k_updF<1, false><<<NN, 256, 0, stream>>>(t);
    }
    // ---- transformer branch ----
    k_attn<<<2456, 256, 0, stream>>>();
    k_ffn<<<1228, 256, 0, stream>>>();
    // ---- combine + conv ----
    k_final<<<dim3(NN, BB), 64, 0, stream>>>(d_out);
}